// Round 8
// baseline (52.316 us; speedup 1.0000x reference)
//
#include <hip/hip_runtime.h>
#include <math.h>

typedef float f32x4 __attribute__((ext_vector_type(4)));
typedef _Float16 f16;
typedef f16 f16x8 __attribute__((ext_vector_type(8)));
typedef unsigned int u32;
typedef u32 u32x2 __attribute__((ext_vector_type(2)));

#define BB 4096
#define TT 200
#define DD 32
#define H1 80
#define H2 40
#define SLAB_W 104   // f16 per slab row: 96 used + 8 pad -> 208B stride

// packed tables (f32) + W2 fragment table (f16), coarse device globals
__device__ __align__(16) float g_BCj[DD * H1];   // (B-C)[k][j]
__device__ __align__(16) float g_Dj [DD * H1];   // D[k][j]
__device__ __align__(16) float g_ACj[DD * H1];   // (A+C)[k][j]
// W2 frags: lane l, elem e of group g=(kt*3+n) holds W2[kt*32+(l>>4)*8+e][n*16+(l&15)]
__device__ __align__(16) f16 g_w2h[9 * 64 * 8];

__device__ __forceinline__ float fast_sigmoid(float x) {
    return __builtin_amdgcn_rcpf(1.f + __expf(-x));
}

__global__ void pack_kernel(const float* __restrict__ W1, const float* __restrict__ W2) {
    int idx = blockIdx.x * 256 + threadIdx.x;
    if (idx < DD * H1) {
        int kk = idx / H1, j = idx % H1;
        g_BCj[idx] = W1[(32 + kk) * H1 + j] - W1[(64 + kk) * H1 + j];
        g_Dj [idx] = W1[(96 + kk) * H1 + j];
        g_ACj[idx] = W1[kk * H1 + j] + W1[(64 + kk) * H1 + j];
        return;
    }
    idx -= DD * H1;
    if (idx < 9 * 64 * 8) {                       // W2 fragments (f16 hi), padded K=96 N=48
        int e = idx & 7, l = (idx >> 3) & 63, g = idx >> 9;
        int kt = g / 3, n = g % 3;
        int j   = kt * 32 + (l >> 4) * 8 + e;     // K index (H1 dim)
        int col = n * 16 + (l & 15);              // N index (H2 dim)
        float v = (j < H1 && col < H2) ? W2[j * H2 + col] : 0.f;
        g_w2h[idx] = (f16)v;
    }
}

// one batch-row per WAVE; L1/L2 software-pipelined via per-wave double slab.
// NO min-waves launch_bounds (R5: forces 64-VGPR cap + spill).
// R8: per-block tile-order rotation de-phases the 4 co-resident waves per SIMD
// (they otherwise run lockstep and contend for the same pipe at the same time);
// s_setprio(1) wraps the L2 MFMA cluster (T5: pays only with phase diversity).
__global__ __launch_bounds__(256) void din_mfma(
    const float* __restrict__ q, const float* __restrict__ k, const int* __restrict__ mask,
    const float* __restrict__ Wq, const float* __restrict__ bq, const float* __restrict__ alpha,
    const float* __restrict__ b1, const float* __restrict__ b2, const float* __restrict__ Wf,
    float* __restrict__ out)
{
    const int tid = threadIdx.x;
    const int wid = tid >> 6, l = tid & 63;
    const int l15 = l & 15, lg4 = l >> 4;
    const int b   = (blockIdx.x << 2) | wid;      // this wave's batch row

    __shared__ __align__(16) f16   slab[4][2][16][SLAB_W]; // per-wave DOUBLE-buffered sg
    __shared__ __align__(16) f16   w2h_s[9 * 64 * 8];      // W2 fragments (block-shared)
    __shared__ __align__(16) float u_s[4][H1];
    __shared__ __align__(16) float lgt[4][208];
    // qp aliased into lgt (lgt written only in main loop; qp dead by then)
    float* qp = lgt[wid];

    // ---- stage W2 frags -> LDS (only cross-wave dependency) ----
    {
        const u32* src = (const u32*)g_w2h;       // 2304 u32 = 9 * 256
        u32* dst = (u32*)w2h_s;
        #pragma unroll
        for (int i = 0; i < 9; ++i) dst[i * 256 + tid] = src[i * 256 + tid];
    }

    // hoist mask row loads: HBM latency hides under the main loop
    const int* mrow = mask + (size_t)b * TT;
    int mk0 = mrow[l];
    int mk1 = mrow[64 + l];
    int mk2 = mrow[128 + l];
    int mk3 = (l < 8) ? mrow[192 + l] : 1;

    // ---- phase 0a (per wave): qp = prelu(q[b] @ Wq + bq) ----
    if (l < DD) {
        const float* qr = q + (size_t)b * DD;
        float acc = bq[l];
        #pragma unroll
        for (int e = 0; e < DD; ++e) acc += qr[e] * Wq[e * DD + l];
        float a = alpha[l];
        qp[l] = acc >= 0.f ? acc : a * acc;
    }
    // zero pad cols j=80..95 of BOTH buffers (kt=2 reads them; W2 frags are 0 there)
    {
        u32* z0 = (u32*)slab[wid][0];
        u32* z1 = (u32*)slab[wid][1];
        #pragma unroll
        for (int i = 0; i < 2; ++i) {
            int idx = i * 64 + l;                 // 0..127 = 16 rows x 8 u32
            int off = (idx >> 3) * 52 + 40 + (idx & 7);
            z0[off] = 0u;
            z1[off] = 0u;
        }
    }

    // ---- phase 0b (per wave): u[j] = b1[j] + qp.(A+C)[:,j] ----
    #pragma unroll
    for (int i = 0; i < 2; ++i) {
        int c = i * 64 + l;
        if (c < H1) {
            float acc = b1[c];
            #pragma unroll
            for (int d = 0; d < DD; ++d) acc += qp[d] * g_ACj[d * H1 + c];
            u_s[wid][c] = acc;
        }
    }
    // L1 A-operand frags (W1'): [j=n*16+l15][d=lg4*8+e], f16 hi/lo (keep B-lo guard)
    f16x8 Bh[5], Bl[5];
    #pragma unroll
    for (int n = 0; n < 5; ++n) {
        #pragma unroll
        for (int e = 0; e < 8; ++e) {
            int kidx = lg4 * 8 + e;
            int j = n * 16 + l15;
            float v = g_BCj[kidx * H1 + j] + qp[kidx] * g_Dj[kidx * H1 + j];
            f16 hi = (f16)v;
            Bh[n][e] = hi;
            Bl[n][e] = (f16)(v - (float)hi);
        }
    }
    // per-lane b2/Wf quads for transposed L2: lane owns H2 cols c0..c0+3, c0=n*16+lg4*4
    f32x4 b2r[3], wfr[3];
    #pragma unroll
    for (int n = 0; n < 3; ++n) {
        int c0 = n * 16 + lg4 * 4;
        if (c0 + 3 < H2) {
            b2r[n] = *(const f32x4*)(b2 + c0);
            wfr[n] = *(const f32x4*)(Wf + c0);
        } else {
            b2r[n] = (f32x4){0.f, 0.f, 0.f, 0.f};
            wfr[n] = (f32x4){0.f, 0.f, 0.f, 0.f};
        }
    }
    // u -> registers: lane needs u[j0..j0+3] per n-tile (acc init)
    f32x4 ur[5];
    #pragma unroll
    for (int n = 0; n < 5; ++n) ur[n] = *(const f32x4*)(&u_s[wid][n * 16 + lg4 * 4]);

    __syncthreads();   // only barrier: w2h_s visible to all waves

    // ---- main loop: 13 m-tiles, 2-stage pipeline, per-block phase rotation ----
    const float* kb = k + (size_t)b * (TT * DD);
    f16 (*ws0)[SLAB_W] = slab[wid][0];
    f16 (*ws1)[SLAB_W] = slab[wid][1];
    float* lg = lgt[wid];

    const int phase = blockIdx.x % 13;            // de-phases co-resident waves
    auto tileof = [&](int i) { int m = i + phase; return m >= 13 ? m - 13 : m; };

    f32x4 x0, x1;
    auto loadk = [&](int m) {
        int t = m * 16 + l15; if (t > TT - 1) t = TT - 1;
        const f32x4* kr = (const f32x4*)(kb + t * DD + lg4 * 8);
        x0 = kr[0]; x1 = kr[1];
    };

    // L1 stage for the tile currently in x0/x1; optional prefetch of tile nload
    auto l1_full = [&](f16 (*wbuf)[SLAB_W], int nload) {
        f16x8 Ah;
        #pragma unroll
        for (int e = 0; e < 4; ++e) {
            Ah[e]     = (f16)x0[e];
            Ah[e + 4] = (f16)x1[e];
        }
        if (nload >= 0) loadk(nload);
        #pragma unroll
        for (int n = 0; n < 5; ++n) {
            int j0 = n * 16 + lg4 * 4;
            f32x4 acc = ur[n];                            // bias+u from regs
            acc = __builtin_amdgcn_mfma_f32_16x16x32_f16(Bh[n], Ah, acc, 0, 0, 0);
            acc = __builtin_amdgcn_mfma_f32_16x16x32_f16(Bl[n], Ah, acc, 0, 0, 0);
            auto p01 = __builtin_amdgcn_cvt_pkrtz(fast_sigmoid(acc[0]), fast_sigmoid(acc[1]));
            auto p23 = __builtin_amdgcn_cvt_pkrtz(fast_sigmoid(acc[2]), fast_sigmoid(acc[3]));
            u32x2 w;
            w[0] = __builtin_bit_cast(u32, p01);
            w[1] = __builtin_bit_cast(u32, p23);
            *(u32x2*)(&wbuf[l15][j0]) = w;
        }
    };

    // body(i,m): L2 (transposed) for tile m from rbuf, overlapped with L1 for the
    // next tile into wbuf. i = pipeline position (controls prologue/epilogue),
    // m = actual tile index (rotated).
    auto body = [&](int i, int m, f16 (*rbuf)[SLAB_W], f16 (*wbuf)[SLAB_W]) {
        // slab reads: data one full iteration old -> latency fully hidden
        f16x8 sh0 = *(const f16x8*)(&rbuf[l15][0 * 32 + lg4 * 8]);
        f16x8 sh1 = *(const f16x8*)(&rbuf[l15][1 * 32 + lg4 * 8]);
        f16x8 sh2 = *(const f16x8*)(&rbuf[l15][2 * 32 + lg4 * 8]);

        if (i < 12) l1_full(wbuf, i < 11 ? tileof(i + 2) : -1);

        __builtin_amdgcn_s_setprio(1);
        f32x4 a0 = {0.f,0.f,0.f,0.f}, a1 = {0.f,0.f,0.f,0.f}, a2 = {0.f,0.f,0.f,0.f};
        #pragma unroll
        for (int kt = 0; kt < 3; ++kt) {
            f16x8 w0 = *(const f16x8*)(w2h_s + ((kt * 3 + 0) * 64 + l) * 8);
            f16x8 w1 = *(const f16x8*)(w2h_s + ((kt * 3 + 1) * 64 + l) * 8);
            f16x8 w2 = *(const f16x8*)(w2h_s + ((kt * 3 + 2) * 64 + l) * 8);
            f16x8 sh = (kt == 0) ? sh0 : (kt == 1) ? sh1 : sh2;
            a0 = __builtin_amdgcn_mfma_f32_16x16x32_f16(w0, sh, a0, 0, 0, 0);
            a1 = __builtin_amdgcn_mfma_f32_16x16x32_f16(w1, sh, a1, 0, 0, 0);
            a2 = __builtin_amdgcn_mfma_f32_16x16x32_f16(w2, sh, a2, 0, 0, 0);
        }
        __builtin_amdgcn_s_setprio(0);

        float p = 0.f;
        #pragma unroll
        for (int n = 0; n < 3; ++n) {
            f32x4 av = (n == 0) ? a0 : (n == 1) ? a1 : a2;
            p += wfr[n][0] * fast_sigmoid(av[0] + b2r[n][0]);
            p += wfr[n][1] * fast_sigmoid(av[1] + b2r[n][1]);
            p += wfr[n][2] * fast_sigmoid(av[2] + b2r[n][2]);
            p += wfr[n][3] * fast_sigmoid(av[3] + b2r[n][3]);
        }
        p += __shfl_xor(p, 16);
        p += __shfl_xor(p, 32);
        if (l < 16) lg[m * 16 + l15] = p;
    };

    // prologue: L1(tile(0)) -> ws0, then x holds tile(1)
    loadk(tileof(0));
    l1_full(ws0, tileof(1));

    for (int i = 0; i < 13; i += 2) {
        body(i, tileof(i), ws0, ws1);
        if (i + 1 < 13) body(i + 1, tileof(i + 1), ws1, ws0);
    }

    // ---- per-wave masked softmax over t<200 (wave-local lgt; mask preloaded) ----
    const float NEG = -4294967295.0f;             // -2^32+1
    float v0 = lg[l];        if (mk0 == 0) v0 = NEG;
    float v1 = lg[64 + l];   if (mk1 == 0) v1 = NEG;
    float v2 = lg[128 + l];  if (mk2 == 0) v2 = NEG;
    float v3 = -8589934590.0f;
    if (l < 8) { v3 = lg[192 + l]; if (mk3 == 0) v3 = NEG; }

    float mx = fmaxf(fmaxf(v0, v1), fmaxf(v2, v3));
    #pragma unroll
    for (int off = 32; off; off >>= 1) mx = fmaxf(mx, __shfl_xor(mx, off));

    float e0 = __expf(v0 - mx), e1 = __expf(v1 - mx);
    float e2 = __expf(v2 - mx), e3 = __expf(v3 - mx);   // pad lanes underflow to 0
    float s = (e0 + e1) + (e2 + e3);
    #pragma unroll
    for (int off = 32; off; off >>= 1) s += __shfl_xor(s, off);

    float* orow = out + (size_t)b * TT;
    orow[l]       = e0 / s;
    orow[64 + l]  = e1 / s;
    orow[128 + l] = e2 / s;
    if (l < 8) orow[192 + l] = e3 / s;
}

extern "C" void kernel_launch(void* const* d_in, const int* in_sizes, int n_in,
                              void* d_out, int out_size, void* d_ws, size_t ws_size,
                              hipStream_t stream) {
    const float* q     = (const float*)d_in[0];
    const float* k     = (const float*)d_in[1];
    // d_in[2] = v : unused by the reference output
    const int*   mask  = (const int*)d_in[3];
    const float* Wq    = (const float*)d_in[4];
    const float* bq    = (const float*)d_in[5];
    const float* alpha = (const float*)d_in[6];
    const float* W1    = (const float*)d_in[7];
    const float* b1    = (const float*)d_in[8];
    const float* W2    = (const float*)d_in[9];
    const float* b2    = (const float*)d_in[10];
    const float* Wf    = (const float*)d_in[11];
    // d_in[12] = bf : dropped (softmax is shift-invariant, incl. all-masked rows)
    float* out = (float*)d_out;

    hipLaunchKernelGGL(pack_kernel, dim3((DD * H1 + 9 * 64 * 8 + 255) / 256), dim3(256),
                       0, stream, W1, W2);
    hipLaunchKernelGGL(din_mfma, dim3(BB / 4), dim3(256), 0, stream,
                       q, k, mask, Wq, bq, alpha, b1, b2, Wf, out);
}

// Round 9
// 48.163 us; speedup vs baseline: 1.0862x; 1.0862x over previous
//
#include <hip/hip_runtime.h>
#include <math.h>

typedef float f32x4 __attribute__((ext_vector_type(4)));
typedef _Float16 f16;
typedef f16 f16x8 __attribute__((ext_vector_type(8)));
typedef unsigned int u32;
typedef u32 u32x2 __attribute__((ext_vector_type(2)));

#define BB 4096
#define TT 200
#define DD 32
#define H1 80
#define H2 40
#define SLAB_W 104   // f16 per slab row: 96 used + 8 pad -> 208B stride

// packed tables (f32) + W2 fragment table (f16), coarse device globals
__device__ __align__(16) float g_BCj[DD * H1];   // (B-C)[k][j]
__device__ __align__(16) float g_Dj [DD * H1];   // D[k][j]
__device__ __align__(16) float g_ACj[DD * H1];   // (A+C)[k][j]
// W2 frags: lane l, elem e of group g=(kt*3+n) holds W2[kt*32+(l>>4)*8+e][n*16+(l&15)]
__device__ __align__(16) f16 g_w2h[9 * 64 * 8];

__device__ __forceinline__ float fast_sigmoid(float x) {
    return __builtin_amdgcn_rcpf(1.f + __expf(-x));
}

__global__ void pack_kernel(const float* __restrict__ W1, const float* __restrict__ W2) {
    int idx = blockIdx.x * 256 + threadIdx.x;
    if (idx < DD * H1) {
        int kk = idx / H1, j = idx % H1;
        g_BCj[idx] = W1[(32 + kk) * H1 + j] - W1[(64 + kk) * H1 + j];
        g_Dj [idx] = W1[(96 + kk) * H1 + j];
        g_ACj[idx] = W1[kk * H1 + j] + W1[(64 + kk) * H1 + j];
        return;
    }
    idx -= DD * H1;
    if (idx < 9 * 64 * 8) {                       // W2 fragments (f16 hi), padded K=96 N=48
        int e = idx & 7, l = (idx >> 3) & 63, g = idx >> 9;
        int kt = g / 3, n = g % 3;
        int j   = kt * 32 + (l >> 4) * 8 + e;     // K index (H1 dim)
        int col = n * 16 + (l & 15);              // N index (H2 dim)
        float v = (j < H1 && col < H2) ? W2[j * H2 + col] : 0.f;
        g_w2h[idx] = (f16)v;
    }
}

// one batch-row per WAVE; L1/L2 software-pipelined via SINGLE-buffered slab:
// per-wave LDS ops execute in order, so body(m)'s sh-reads (tile m) safely precede
// l1_full's overwrite with tile m+1 — no double buffer, no sync.
// NO min-waves launch_bounds (R5: forces 64-VGPR cap + spill).
// R9: Bl guard dropped (L1 = 5 MFMA/tile); R8 rotation/setprio reverted (null).
__global__ __launch_bounds__(256) void din_mfma(
    const float* __restrict__ q, const float* __restrict__ k, const int* __restrict__ mask,
    const float* __restrict__ Wq, const float* __restrict__ bq, const float* __restrict__ alpha,
    const float* __restrict__ b1, const float* __restrict__ b2, const float* __restrict__ Wf,
    float* __restrict__ out)
{
    const int tid = threadIdx.x;
    const int wid = tid >> 6, l = tid & 63;
    const int l15 = l & 15, lg4 = l >> 4;
    const int b   = (blockIdx.x << 2) | wid;      // this wave's batch row

    __shared__ __align__(16) f16   slab[4][16][SLAB_W];   // per-wave sg, SINGLE buffer
    __shared__ __align__(16) f16   w2h_s[9 * 64 * 8];     // W2 fragments (block-shared)
    __shared__ __align__(16) float u_s[4][H1];
    __shared__ __align__(16) float lgt[4][208];
    // qp aliased into lgt (lgt written only in main loop; qp dead by then)
    float* qp = lgt[wid];

    // ---- stage W2 frags -> LDS (only cross-wave dependency) ----
    {
        const u32* src = (const u32*)g_w2h;       // 2304 u32 = 9 * 256
        u32* dst = (u32*)w2h_s;
        #pragma unroll
        for (int i = 0; i < 9; ++i) dst[i * 256 + tid] = src[i * 256 + tid];
    }

    // hoist mask row loads: HBM latency hides under the main loop
    const int* mrow = mask + (size_t)b * TT;
    int mk0 = mrow[l];
    int mk1 = mrow[64 + l];
    int mk2 = mrow[128 + l];
    int mk3 = (l < 8) ? mrow[192 + l] : 1;

    // ---- phase 0a (per wave): qp = prelu(q[b] @ Wq + bq) ----
    if (l < DD) {
        const float* qr = q + (size_t)b * DD;
        float acc = bq[l];
        #pragma unroll
        for (int e = 0; e < DD; ++e) acc += qr[e] * Wq[e * DD + l];
        float a = alpha[l];
        qp[l] = acc >= 0.f ? acc : a * acc;
    }
    // zero pad cols j=80..95 (kt=2 reads them; W2 frags are 0 there)
    {
        u32* z0 = (u32*)slab[wid];                // 52 u32 per row
        #pragma unroll
        for (int i = 0; i < 2; ++i) {
            int idx = i * 64 + l;                 // 0..127 = 16 rows x 8 u32
            z0[(idx >> 3) * 52 + 40 + (idx & 7)] = 0u;
        }
    }

    // ---- phase 0b (per wave): u[j] = b1[j] + qp.(A+C)[:,j] ----
    #pragma unroll
    for (int i = 0; i < 2; ++i) {
        int c = i * 64 + l;
        if (c < H1) {
            float acc = b1[c];
            #pragma unroll
            for (int d = 0; d < DD; ++d) acc += qp[d] * g_ACj[d * H1 + c];
            u_s[wid][c] = acc;
        }
    }
    // L1 A-operand frags (W1'): [j=n*16+l15][d=lg4*8+e], f16 hi only (Bl dropped R9)
    f16x8 Bh[5];
    #pragma unroll
    for (int n = 0; n < 5; ++n) {
        #pragma unroll
        for (int e = 0; e < 8; ++e) {
            int kidx = lg4 * 8 + e;
            int j = n * 16 + l15;
            Bh[n][e] = (f16)(g_BCj[kidx * H1 + j] + qp[kidx] * g_Dj[kidx * H1 + j]);
        }
    }
    // per-lane b2/Wf quads for transposed L2: lane owns H2 cols c0..c0+3, c0=n*16+lg4*4
    f32x4 b2r[3], wfr[3];
    #pragma unroll
    for (int n = 0; n < 3; ++n) {
        int c0 = n * 16 + lg4 * 4;
        if (c0 + 3 < H2) {
            b2r[n] = *(const f32x4*)(b2 + c0);
            wfr[n] = *(const f32x4*)(Wf + c0);
        } else {
            b2r[n] = (f32x4){0.f, 0.f, 0.f, 0.f};
            wfr[n] = (f32x4){0.f, 0.f, 0.f, 0.f};
        }
    }
    // u -> registers: lane needs u[j0..j0+3] per n-tile (acc init)
    f32x4 ur[5];
    #pragma unroll
    for (int n = 0; n < 5; ++n) ur[n] = *(const f32x4*)(&u_s[wid][n * 16 + lg4 * 4]);

    __syncthreads();   // only barrier: w2h_s visible to all waves

    // ---- main loop: 13 m-tiles, 2-stage pipeline on a single slab buffer ----
    const float* kb = k + (size_t)b * (TT * DD);
    f16 (*ws)[SLAB_W] = slab[wid];
    float* lg = lgt[wid];

    f32x4 x0, x1;
    auto loadk = [&](int m) {
        int t = m * 16 + l15; if (t > TT - 1) t = TT - 1;
        const f32x4* kr = (const f32x4*)(kb + t * DD + lg4 * 8);
        x0 = kr[0]; x1 = kr[1];
    };

    // L1 stage for the tile currently in x0/x1; optional prefetch of tile nload
    auto l1_full = [&](int nload) {
        f16x8 Ah;
        #pragma unroll
        for (int e = 0; e < 4; ++e) {
            Ah[e]     = (f16)x0[e];
            Ah[e + 4] = (f16)x1[e];
        }
        if (nload >= 0) loadk(nload);
        #pragma unroll
        for (int n = 0; n < 5; ++n) {
            int j0 = n * 16 + lg4 * 4;
            f32x4 acc = ur[n];                            // bias+u from regs
            acc = __builtin_amdgcn_mfma_f32_16x16x32_f16(Bh[n], Ah, acc, 0, 0, 0);
            auto p01 = __builtin_amdgcn_cvt_pkrtz(fast_sigmoid(acc[0]), fast_sigmoid(acc[1]));
            auto p23 = __builtin_amdgcn_cvt_pkrtz(fast_sigmoid(acc[2]), fast_sigmoid(acc[3]));
            u32x2 w;
            w[0] = __builtin_bit_cast(u32, p01);
            w[1] = __builtin_bit_cast(u32, p23);
            *(u32x2*)(&ws[l15][j0]) = w;
        }
    };

    // body(m): L2 (transposed) for tile m — sh reads issue BEFORE l1_full's
    // overwriting writes (in-order LDS guarantees old data), then overlapped
    // with L1 for tile m+1.
    auto body = [&](int m) {
        f16x8 sh0 = *(const f16x8*)(&ws[l15][0 * 32 + lg4 * 8]);
        f16x8 sh1 = *(const f16x8*)(&ws[l15][1 * 32 + lg4 * 8]);
        f16x8 sh2 = *(const f16x8*)(&ws[l15][2 * 32 + lg4 * 8]);

        if (m < 12) l1_full(m < 11 ? m + 2 : -1);

        f32x4 a0 = {0.f,0.f,0.f,0.f}, a1 = {0.f,0.f,0.f,0.f}, a2 = {0.f,0.f,0.f,0.f};
        #pragma unroll
        for (int kt = 0; kt < 3; ++kt) {
            f16x8 w0 = *(const f16x8*)(w2h_s + ((kt * 3 + 0) * 64 + l) * 8);
            f16x8 w1 = *(const f16x8*)(w2h_s + ((kt * 3 + 1) * 64 + l) * 8);
            f16x8 w2 = *(const f16x8*)(w2h_s + ((kt * 3 + 2) * 64 + l) * 8);
            f16x8 sh = (kt == 0) ? sh0 : (kt == 1) ? sh1 : sh2;
            a0 = __builtin_amdgcn_mfma_f32_16x16x32_f16(w0, sh, a0, 0, 0, 0);
            a1 = __builtin_amdgcn_mfma_f32_16x16x32_f16(w1, sh, a1, 0, 0, 0);
            a2 = __builtin_amdgcn_mfma_f32_16x16x32_f16(w2, sh, a2, 0, 0, 0);
        }

        float p = 0.f;
        #pragma unroll
        for (int n = 0; n < 3; ++n) {
            f32x4 av = (n == 0) ? a0 : (n == 1) ? a1 : a2;
            p += wfr[n][0] * fast_sigmoid(av[0] + b2r[n][0]);
            p += wfr[n][1] * fast_sigmoid(av[1] + b2r[n][1]);
            p += wfr[n][2] * fast_sigmoid(av[2] + b2r[n][2]);
            p += wfr[n][3] * fast_sigmoid(av[3] + b2r[n][3]);
        }
        p += __shfl_xor(p, 16);
        p += __shfl_xor(p, 32);
        if (l < 16) lg[m * 16 + l15] = p;
    };

    // prologue: L1(0) -> ws (slab holds tile 0), x holds tile 1
    loadk(0);
    l1_full(1);

    for (int m = 0; m < 13; ++m) body(m);

    // ---- per-wave masked softmax over t<200 (wave-local lgt; mask preloaded) ----
    const float NEG = -4294967295.0f;             // -2^32+1
    float v0 = lg[l];        if (mk0 == 0) v0 = NEG;
    float v1 = lg[64 + l];   if (mk1 == 0) v1 = NEG;
    float v2 = lg[128 + l];  if (mk2 == 0) v2 = NEG;
    float v3 = -8589934590.0f;
    if (l < 8) { v3 = lg[192 + l]; if (mk3 == 0) v3 = NEG; }

    float mx = fmaxf(fmaxf(v0, v1), fmaxf(v2, v3));
    #pragma unroll
    for (int off = 32; off; off >>= 1) mx = fmaxf(mx, __shfl_xor(mx, off));

    float e0 = __expf(v0 - mx), e1 = __expf(v1 - mx);
    float e2 = __expf(v2 - mx), e3 = __expf(v3 - mx);   // pad lanes underflow to 0
    float s = (e0 + e1) + (e2 + e3);
    #pragma unroll
    for (int off = 32; off; off >>= 1) s += __shfl_xor(s, off);

    float* orow = out + (size_t)b * TT;
    orow[l]       = e0 / s;
    orow[64 + l]  = e1 / s;
    orow[128 + l] = e2 / s;
    if (l < 8) orow[192 + l] = e3 / s;
}

extern "C" void kernel_launch(void* const* d_in, const int* in_sizes, int n_in,
                              void* d_out, int out_size, void* d_ws, size_t ws_size,
                              hipStream_t stream) {
    const float* q     = (const float*)d_in[0];
    const float* k     = (const float*)d_in[1];
    // d_in[2] = v : unused by the reference output
    const int*   mask  = (const int*)d_in[3];
    const float* Wq    = (const float*)d_in[4];
    const float* bq    = (const float*)d_in[5];
    const float* alpha = (const float*)d_in[6];
    const float* W1    = (const float*)d_in[7];
    const float* b1    = (const float*)d_in[8];
    const float* W2    = (const float*)d_in[9];
    const float* b2    = (const float*)d_in[10];
    const float* Wf    = (const float*)d_in[11];
    // d_in[12] = bf : dropped (softmax is shift-invariant, incl. all-masked rows)
    float* out = (float*)d_out;

    hipLaunchKernelGGL(pack_kernel, dim3((DD * H1 + 9 * 64 * 8 + 255) / 256), dim3(256),
                       0, stream, W1, W2);
    hipLaunchKernelGGL(din_mfma, dim3(BB / 4), dim3(256), 0, stream,
                       q, k, mask, Wq, bq, alpha, b1, b2, Wf, out);
}